// Round 1
// baseline (551.646 us; speedup 1.0000x reference)
//
#include <hip/hip_runtime.h>

// Problem constants (from setup_inputs)
#define BS 8
#define NN 4096
#define NB 8
#define NR 64
#define ND 256
#define TN 128        // n-rows per block-tile (8 waves x 16 rows)
#define QPAD 264      // row stride (elems) for qbf/Kb: 256 + 8 pad -> 528 B, 16B-aligned
#define SPAD 72       // row stride (elems) for Vt/Ssm: 64 + 8 pad -> 144 B, 16B-aligned

typedef __attribute__((ext_vector_type(8))) short bf16x8;
typedef __attribute__((ext_vector_type(4))) float f32x4;

__device__ __forceinline__ unsigned short f2bf(float f) {
    unsigned int u = __builtin_bit_cast(unsigned int, f);
    u += 0x7fffu + ((u >> 16) & 1u);          // round-to-nearest-even
    return (unsigned short)(u >> 16);
}
__device__ __forceinline__ float bf2f(unsigned short h) {
    unsigned int u = ((unsigned int)h) << 16;
    return __builtin_bit_cast(float, u);
}

// grid = 256 blocks (64 (s,b) pairs x 4 chunks), block = 512 threads (8 waves).
// Wave-decoupled: after one staging barrier (K/V/a), each wave runs an
// independent 8-iteration pipeline over its own 16 q-rows per iteration:
//   prefetch q(t+1) to regs || GEMM1 from reg-fragments -> W -> GEMM2 (swapped:
//   O^T, row=d col=n) -> float4 stores.  qbf/Ssm rows are wave-private bands;
//   NO per-iteration __syncthreads.
__global__ __launch_bounds__(512, 2)
void holo_read_kernel(const float* __restrict__ q,
                      const float* __restrict__ pmK,
                      const float* __restrict__ pmV,
                      const float* __restrict__ pma,
                      float* __restrict__ out)
{
    __shared__ __attribute__((aligned(16))) unsigned short qbf[TN][QPAD];  // q bf16, wave-private 16-row bands (epilogue source)
    __shared__ __attribute__((aligned(16))) unsigned short Kb[NR][QPAD];   // K, bf16 (read-only after barrier)
    __shared__ __attribute__((aligned(16))) unsigned short Vt[ND][SPAD];   // V transposed [d][r] (read-only after barrier)
    __shared__ __attribute__((aligned(16))) unsigned short Ssm[TN][SPAD];  // W = a[r]*S, bf16, wave-private bands
    __shared__ float a_sh[NR];

    const int tid  = threadIdx.x;
    const int lane = tid & 63;
    const int w    = tid >> 6;      // wave id 0..7
    const int ln15 = lane & 15;
    const int quad = lane >> 4;

    const int sbi   = blockIdx.x & 63;   // same-sb blocks 64 apart -> same XCD (RR%8)
    const int chunk = blockIdx.x >> 6;   // 0..3
    const int s     = sbi >> 3;
    const int b     = sbi & 7;

    const int myrow = w * 16 + ln15;                 // row within 128-tile; qbf/Ssm band row
    const size_t row_stride = (size_t)NB * ND;       // floats between consecutive n
    const float* qbase = q   + ((size_t)(s * NN + chunk * 1024 + myrow) * NB + b) * ND + quad * 8;
    float*       obase = out + ((size_t)(s * NN + chunk * 1024 + myrow) * NB + b) * ND;

    // ---- prefetch iteration 0 (A-fragment layout: lane owns row myrow, cols 32*kk+8*quad..+7) ----
    float4 pf[16];
    {
        const float* p = qbase;
        #pragma unroll
        for (int kk = 0; kk < 8; ++kk) {
            pf[2 * kk]     = *(const float4*)(p + kk * 32);
            pf[2 * kk + 1] = *(const float4*)(p + kk * 32 + 4);
        }
    }

    // ---- stage a, K, V (once per block; only barrier in the kernel) ----
    if (tid < NR) a_sh[tid] = pma[sbi * NR + tid];
    const size_t kvbase = (size_t)sbi * NR * ND;
    for (int rr = w; rr < NR; rr += 8) {
        const float4 kv = *(const float4*)&pmK[kvbase + (size_t)rr * ND + lane * 4];
        ushort4 uk;
        uk.x = f2bf(kv.x); uk.y = f2bf(kv.y); uk.z = f2bf(kv.z); uk.w = f2bf(kv.w);
        *(ushort4*)&Kb[rr][lane * 4] = uk;
        const float4 vv = *(const float4*)&pmV[kvbase + (size_t)rr * ND + lane * 4];
        Vt[lane * 4 + 0][rr] = f2bf(vv.x);
        Vt[lane * 4 + 1][rr] = f2bf(vv.y);
        Vt[lane * 4 + 2][rr] = f2bf(vv.z);
        Vt[lane * 4 + 3][rr] = f2bf(vv.w);
    }
    __syncthreads();

    float ar[4];
    #pragma unroll
    for (int rt = 0; rt < 4; ++rt) ar[rt] = a_sh[rt * 16 + ln15];

    for (int it = 0; it < 8; ++it) {
        // ---- consume prefetch: partial ||q||^2, bf16 fragments, qbf band write ----
        float ss = 0.f;
        bf16x8 qfrag[8];
        #pragma unroll
        for (int kk = 0; kk < 8; ++kk) {
            const float4 v0 = pf[2 * kk], v1 = pf[2 * kk + 1];
            ss += v0.x * v0.x + v0.y * v0.y + v0.z * v0.z + v0.w * v0.w
                + v1.x * v1.x + v1.y * v1.y + v1.z * v1.z + v1.w * v1.w;
            bf16x8 f;
            f[0] = (short)f2bf(v0.x); f[1] = (short)f2bf(v0.y);
            f[2] = (short)f2bf(v0.z); f[3] = (short)f2bf(v0.w);
            f[4] = (short)f2bf(v1.x); f[5] = (short)f2bf(v1.y);
            f[6] = (short)f2bf(v1.z); f[7] = (short)f2bf(v1.w);
            qfrag[kk] = f;
            *(bf16x8*)&qbf[myrow][kk * 32 + quad * 8] = f;   // wave-private band: no barrier
        }

        // ---- issue next iteration's q loads early (hidden under GEMM1+GEMM2) ----
        if (it < 7) {
            const float* p = qbase + (size_t)(it + 1) * 128 * row_stride;
            #pragma unroll
            for (int kk = 0; kk < 8; ++kk) {
                pf[2 * kk]     = *(const float4*)(p + kk * 32);
                pf[2 * kk + 1] = *(const float4*)(p + kk * 32 + 4);
            }
        }

        // ---- full row norm: lane holds 64 elems of its row; reduce across 4 quads ----
        ss += __shfl_xor(ss, 16, 64);
        ss += __shfl_xor(ss, 32, 64);
        const float inv = 1.0f / fmaxf(sqrtf(ss), 1e-8f);   // folded into epilogue

        // ---- GEMM1: S[16w..+15][0..63] = q_tile @ K^T (A-frags from registers) ----
        f32x4 accS[4];
        #pragma unroll
        for (int rt = 0; rt < 4; ++rt) accS[rt] = (f32x4){0.f, 0.f, 0.f, 0.f};
        #pragma unroll
        for (int kk = 0; kk < 8; ++kk) {
            #pragma unroll
            for (int rt = 0; rt < 4; ++rt) {
                const bf16x8 bfr = *(const bf16x8*)&Kb[rt * 16 + ln15][kk * 32 + quad * 8];
                accS[rt] = __builtin_amdgcn_mfma_f32_16x16x32_bf16(qfrag[kk], bfr, accS[rt], 0, 0, 0);
            }
        }
        // scale by a[r] only (invn deferred), store W to wave-private Ssm band
        #pragma unroll
        for (int rt = 0; rt < 4; ++rt) {
            #pragma unroll
            for (int reg = 0; reg < 4; ++reg) {
                Ssm[w * 16 + quad * 4 + reg][rt * 16 + ln15] = f2bf(accS[rt][reg] * ar[rt]);
            }
        }

        // ---- GEMM2 (operand-swapped): O^T[d][n] = V[d][r] . W[n][r]; row=d, col=n ----
        f32x4 accO[16];
        #pragma unroll
        for (int dt = 0; dt < 16; ++dt) accO[dt] = (f32x4){0.f, 0.f, 0.f, 0.f};
        #pragma unroll
        for (int kt = 0; kt < 2; ++kt) {
            const bf16x8 aw = *(const bf16x8*)&Ssm[myrow][kt * 32 + quad * 8];
            #pragma unroll
            for (int dt = 0; dt < 16; ++dt) {
                const bf16x8 bv = *(const bf16x8*)&Vt[dt * 16 + ln15][kt * 32 + quad * 8];
                accO[dt] = __builtin_amdgcn_mfma_f32_16x16x32_bf16(bv, aw, accO[dt], 0, 0, 0);
            }
        }

        // ---- epilogue: out[n][d] = q_bf[n][d] * inv[n] * O^T[d][n]; float4 stores ----
        float* op = obase + (size_t)it * 128 * row_stride;
        #pragma unroll
        for (int dt = 0; dt < 16; ++dt) {
            const ushort4 qb = *(const ushort4*)&qbf[myrow][dt * 16 + quad * 4];
            float4 o;
            o.x = bf2f(qb.x) * (inv * accO[dt][0]);
            o.y = bf2f(qb.y) * (inv * accO[dt][1]);
            o.z = bf2f(qb.z) * (inv * accO[dt][2]);
            o.w = bf2f(qb.w) * (inv * accO[dt][3]);
            *(float4*)(op + dt * 16 + quad * 4) = o;
        }
        // no barrier: next iteration's qbf/Ssm writes are same-wave, in program order
    }
}

extern "C" void kernel_launch(void* const* d_in, const int* in_sizes, int n_in,
                              void* d_out, int out_size, void* d_ws, size_t ws_size,
                              hipStream_t stream) {
    const float* q   = (const float*)d_in[0];
    const float* pmK = (const float*)d_in[1];
    const float* pmV = (const float*)d_in[2];
    const float* pma = (const float*)d_in[3];
    float* out = (float*)d_out;
    (void)in_sizes; (void)n_in; (void)out_size; (void)d_ws; (void)ws_size;
    hipLaunchKernelGGL(holo_read_kernel, dim3(256), dim3(512), 0, stream,
                       q, pmK, pmV, pma, out);
}

// Round 2
// 456.945 us; speedup vs baseline: 1.2072x; 1.2072x over previous
//
#include <hip/hip_runtime.h>

// Problem constants (from setup_inputs)
#define BS 8
#define NN 4096
#define NB 8
#define NR 64
#define ND 256
#define TN 128        // n-rows per block-tile (8 waves x 16 rows)
#define QPAD 264      // row stride (elems) for qbf/Kb: 256 + 8 pad -> 528 B, 16B-aligned
#define SPAD 72       // row stride (elems) for Vt/Ssm: 64 + 8 pad -> 144 B, 16B-aligned

typedef __attribute__((ext_vector_type(8))) short bf16x8;
typedef __attribute__((ext_vector_type(4))) float f32x4;

__device__ __forceinline__ unsigned short f2bf(float f) {
    unsigned int u = __builtin_bit_cast(unsigned int, f);
    u += 0x7fffu + ((u >> 16) & 1u);          // round-to-nearest-even
    return (unsigned short)(u >> 16);
}
__device__ __forceinline__ float bf2f(unsigned short h) {
    unsigned int u = ((unsigned int)h) << 16;
    return __builtin_bit_cast(float, u);
}

// grid = 256 blocks (64 (s,b) pairs x 4 chunks), block = 512 threads (8 waves).
// Wave-decoupled (one staging barrier only).  Register-pressure-shaped pipeline:
//   GEMM1 consumes prefetch inline (pf dies progressively, no qfrag array),
//   next-tile prefetch reuses pf right after GEMM1,
//   GEMM2 + epilogue split into two d-halves of accO[8] (32 VGPR each),
//   sched_barrier(0) fences stop the scheduler from re-merging live ranges.
// Peak live ~120-130 VGPR -> no scratch spills (R1 failure mode).
__global__ __launch_bounds__(512, 2)
void holo_read_kernel(const float* __restrict__ q,
                      const float* __restrict__ pmK,
                      const float* __restrict__ pmV,
                      const float* __restrict__ pma,
                      float* __restrict__ out)
{
    __shared__ __attribute__((aligned(16))) unsigned short qbf[TN][QPAD];  // q bf16, wave-private 16-row bands (epilogue source)
    __shared__ __attribute__((aligned(16))) unsigned short Kb[NR][QPAD];   // K, bf16 (read-only after barrier)
    __shared__ __attribute__((aligned(16))) unsigned short Vt[ND][SPAD];   // V transposed [d][r] (read-only after barrier)
    __shared__ __attribute__((aligned(16))) unsigned short Ssm[TN][SPAD];  // W = a[r]*S, bf16, wave-private bands
    __shared__ float a_sh[NR];

    const int tid  = threadIdx.x;
    const int lane = tid & 63;
    const int w    = tid >> 6;      // wave id 0..7
    const int ln15 = lane & 15;
    const int quad = lane >> 4;

    const int sbi   = blockIdx.x & 63;   // same-sb blocks 64 apart -> same XCD (RR%8)
    const int chunk = blockIdx.x >> 6;   // 0..3
    const int s     = sbi >> 3;
    const int b     = sbi & 7;

    const int myrow = w * 16 + ln15;                 // row within 128-tile; qbf/Ssm band row
    const size_t row_stride = (size_t)NB * ND;       // floats between consecutive n
    const float* qbase = q   + ((size_t)(s * NN + chunk * 1024 + myrow) * NB + b) * ND + quad * 8;
    float*       obase = out + ((size_t)(s * NN + chunk * 1024 + myrow) * NB + b) * ND;

    // ---- prefetch iteration 0 (A-fragment layout: lane owns row myrow, cols 32*kk+8*quad..+7) ----
    float4 pf[16];
    {
        const float* p = qbase;
        #pragma unroll
        for (int kk = 0; kk < 8; ++kk) {
            pf[2 * kk]     = *(const float4*)(p + kk * 32);
            pf[2 * kk + 1] = *(const float4*)(p + kk * 32 + 4);
        }
    }

    // ---- stage a, K, V (once per block; only barrier in the kernel) ----
    if (tid < NR) a_sh[tid] = pma[sbi * NR + tid];
    const size_t kvbase = (size_t)sbi * NR * ND;
    for (int rr = w; rr < NR; rr += 8) {
        const float4 kv = *(const float4*)&pmK[kvbase + (size_t)rr * ND + lane * 4];
        ushort4 uk;
        uk.x = f2bf(kv.x); uk.y = f2bf(kv.y); uk.z = f2bf(kv.z); uk.w = f2bf(kv.w);
        *(ushort4*)&Kb[rr][lane * 4] = uk;
        const float4 vv = *(const float4*)&pmV[kvbase + (size_t)rr * ND + lane * 4];
        Vt[lane * 4 + 0][rr] = f2bf(vv.x);
        Vt[lane * 4 + 1][rr] = f2bf(vv.y);
        Vt[lane * 4 + 2][rr] = f2bf(vv.z);
        Vt[lane * 4 + 3][rr] = f2bf(vv.w);
    }
    __syncthreads();

    float ar[4];
    #pragma unroll
    for (int rt = 0; rt < 4; ++rt) ar[rt] = a_sh[rt * 16 + ln15];

    for (int it = 0; it < 8; ++it) {
        // ---- GEMM1 with inline prefetch-consume: pf -> bf16 frag -> MFMA, per kk ----
        float ss = 0.f;
        f32x4 accS[4];
        #pragma unroll
        for (int rt = 0; rt < 4; ++rt) accS[rt] = (f32x4){0.f, 0.f, 0.f, 0.f};

        #pragma unroll
        for (int kk = 0; kk < 8; ++kk) {
            const float4 v0 = pf[2 * kk], v1 = pf[2 * kk + 1];
            ss += v0.x * v0.x + v0.y * v0.y + v0.z * v0.z + v0.w * v0.w
                + v1.x * v1.x + v1.y * v1.y + v1.z * v1.z + v1.w * v1.w;
            bf16x8 f;
            f[0] = (short)f2bf(v0.x); f[1] = (short)f2bf(v0.y);
            f[2] = (short)f2bf(v0.z); f[3] = (short)f2bf(v0.w);
            f[4] = (short)f2bf(v1.x); f[5] = (short)f2bf(v1.y);
            f[6] = (short)f2bf(v1.z); f[7] = (short)f2bf(v1.w);
            *(bf16x8*)&qbf[myrow][kk * 32 + quad * 8] = f;   // wave-private band: no barrier
            #pragma unroll
            for (int rt = 0; rt < 4; ++rt) {
                const bf16x8 bfr = *(const bf16x8*)&Kb[rt * 16 + ln15][kk * 32 + quad * 8];
                accS[rt] = __builtin_amdgcn_mfma_f32_16x16x32_bf16(f, bfr, accS[rt], 0, 0, 0);
            }
        }

        // ---- full row norm: quads of same ln15 hold the 4 column-slices of myrow ----
        ss += __shfl_xor(ss, 16, 64);
        ss += __shfl_xor(ss, 32, 64);
        const float inv = 1.0f / fmaxf(sqrtf(ss), 1e-8f);   // folded into epilogue

        // ---- issue next iteration's q loads now (pf regs just died); hidden under GEMM2 ----
        if (it < 7) {
            const float* p = qbase + (size_t)(it + 1) * 128 * row_stride;
            #pragma unroll
            for (int kk = 0; kk < 8; ++kk) {
                pf[2 * kk]     = *(const float4*)(p + kk * 32);
                pf[2 * kk + 1] = *(const float4*)(p + kk * 32 + 4);
            }
        }
        __builtin_amdgcn_sched_barrier(0);   // pin prefetch issue here; don't sink into GEMM2

        // scale by a[r] only (invn deferred), store W to wave-private Ssm band
        #pragma unroll
        for (int rt = 0; rt < 4; ++rt) {
            #pragma unroll
            for (int reg = 0; reg < 4; ++reg) {
                Ssm[w * 16 + quad * 4 + reg][rt * 16 + ln15] = f2bf(accS[rt][reg] * ar[rt]);
            }
        }

        // A-operand fragments for GEMM2 (wave-private Ssm band, program-order safe)
        const bf16x8 aw0 = *(const bf16x8*)&Ssm[myrow][quad * 8];
        const bf16x8 aw1 = *(const bf16x8*)&Ssm[myrow][32 + quad * 8];

        float* op = obase + (size_t)it * 128 * row_stride;

        // ---- GEMM2 half A (swapped operands: O^T, row=d col=n), dt 0..7 + epilogue ----
        {
            f32x4 accO[8];
            #pragma unroll
            for (int i = 0; i < 8; ++i) accO[i] = (f32x4){0.f, 0.f, 0.f, 0.f};
            #pragma unroll
            for (int dt = 0; dt < 8; ++dt) {
                const bf16x8 bv0 = *(const bf16x8*)&Vt[dt * 16 + ln15][quad * 8];
                const bf16x8 bv1 = *(const bf16x8*)&Vt[dt * 16 + ln15][32 + quad * 8];
                accO[dt] = __builtin_amdgcn_mfma_f32_16x16x32_bf16(bv0, aw0, accO[dt], 0, 0, 0);
                accO[dt] = __builtin_amdgcn_mfma_f32_16x16x32_bf16(bv1, aw1, accO[dt], 0, 0, 0);
            }
            #pragma unroll
            for (int dt = 0; dt < 8; ++dt) {
                const ushort4 qb = *(const ushort4*)&qbf[myrow][dt * 16 + quad * 4];
                float4 o;
                o.x = bf2f(qb.x) * (inv * accO[dt][0]);
                o.y = bf2f(qb.y) * (inv * accO[dt][1]);
                o.z = bf2f(qb.z) * (inv * accO[dt][2]);
                o.w = bf2f(qb.w) * (inv * accO[dt][3]);
                *(float4*)(op + dt * 16 + quad * 4) = o;
            }
        }
        __builtin_amdgcn_sched_barrier(0);   // keep half B's accO from overlapping half A's

        // ---- GEMM2 half B, dt 8..15 + epilogue ----
        {
            f32x4 accO[8];
            #pragma unroll
            for (int i = 0; i < 8; ++i) accO[i] = (f32x4){0.f, 0.f, 0.f, 0.f};
            #pragma unroll
            for (int dt8 = 0; dt8 < 8; ++dt8) {
                const int dt = dt8 + 8;
                const bf16x8 bv0 = *(const bf16x8*)&Vt[dt * 16 + ln15][quad * 8];
                const bf16x8 bv1 = *(const bf16x8*)&Vt[dt * 16 + ln15][32 + quad * 8];
                accO[dt8] = __builtin_amdgcn_mfma_f32_16x16x32_bf16(bv0, aw0, accO[dt8], 0, 0, 0);
                accO[dt8] = __builtin_amdgcn_mfma_f32_16x16x32_bf16(bv1, aw1, accO[dt8], 0, 0, 0);
            }
            #pragma unroll
            for (int dt8 = 0; dt8 < 8; ++dt8) {
                const int dt = dt8 + 8;
                const ushort4 qb = *(const ushort4*)&qbf[myrow][dt * 16 + quad * 4];
                float4 o;
                o.x = bf2f(qb.x) * (inv * accO[dt8][0]);
                o.y = bf2f(qb.y) * (inv * accO[dt8][1]);
                o.z = bf2f(qb.z) * (inv * accO[dt8][2]);
                o.w = bf2f(qb.w) * (inv * accO[dt8][3]);
                *(float4*)(op + dt * 16 + quad * 4) = o;
            }
        }
        // no barrier: next iteration's qbf/Ssm writes are same-wave, in program order
    }
}

extern "C" void kernel_launch(void* const* d_in, const int* in_sizes, int n_in,
                              void* d_out, int out_size, void* d_ws, size_t ws_size,
                              hipStream_t stream) {
    const float* q   = (const float*)d_in[0];
    const float* pmK = (const float*)d_in[1];
    const float* pmV = (const float*)d_in[2];
    const float* pma = (const float*)d_in[3];
    float* out = (float*)d_out;
    (void)in_sizes; (void)n_in; (void)out_size; (void)d_ws; (void)ws_size;
    hipLaunchKernelGGL(holo_read_kernel, dim3(256), dim3(512), 0, stream,
                       q, pmK, pmV, pma, out);
}